// Round 3
// baseline (3467.572 us; speedup 1.0000x reference)
//
#include <hip/hip_runtime.h>
#include <hip/hip_bf16.h>
#include <math.h>

#define B_ 8
#define N_ 1024
#define C_ 256
#define H_ 8
#define D_ 32
#define F_ 682
#define EPS_ 1e-3f

typedef const __hip_bfloat16* bf16cp;
typedef __hip_bfloat16 bf16;

__device__ __forceinline__ float b2f(bf16 v){ return __bfloat162float(v); }
__device__ __forceinline__ float us2f(unsigned int u){ return __uint_as_float(u << 16); }

// flag-aware load: bf=1 -> bf16, bf=0 -> f32
__device__ __forceinline__ float ldf(const void* p, size_t i, int bf){
  return bf ? b2f(((bf16cp)p)[i]) : ((const float*)p)[i];
}

struct Ptrs { const void* p[22]; };

// ---------------- per-tensor dtype sniffer ----------------
__global__ void k_sniff(Ptrs ptrs, int* flags){
  if (threadIdx.x != 0 || blockIdx.x != 0) return;
  const int sizes[22] = {2097152, 8388608, 8388608, 196608, 768, 64, 8, 64, 8,
                         65536, 256, 256, 256, 256, 256, 256, 256,
                         174592, 174592, 174592, 682, 682};
  for (int i = 0; i < 22; i++){
    if (i == 1){ flags[i] = 0; continue; }   // mask handled separately
    const unsigned short* u = (const unsigned short*)ptrs.p[i];
    int nu = sizes[i] < 64 ? sizes[i] : 64;  // safe under bf16 (smaller) footprint
    int badB = 0, badF = 0, evenAllZero = 1, oddAny = 0;
    for (int j = 0; j < nu; j++){
      unsigned short x = u[j];
      float vb = us2f((unsigned int)x);
      float ab = fabsf(vb);
      if (!(vb == 0.0f) && (!(ab <= 1e3f) || ab < 1e-30f || vb != vb)) badB++;
      if ((j & 1) == 0){ if (x) evenAllZero = 0; }
      else            { if (x) oddAny = 1; }
    }
    for (int j = 0; j + 1 < nu; j += 2){
      unsigned int w = ((unsigned int)u[j]) | (((unsigned int)u[j+1]) << 16);
      float vf = __uint_as_float(w);
      float af = fabsf(vf);
      if (!(vf == 0.0f) && (!(af <= 1e3f) || af < 1e-30f || vf != vf)) badF++;
    }
    int bf;
    if (badB > badF) bf = 0;
    else if (badF > badB) bf = 1;
    else bf = (evenAllZero && oddAny) ? 0 : 1;
    flags[i] = bf;
  }
}

// ---------------- lengths from mask diagonal (dtype auto-detect) ----------------
__global__ __launch_bounds__(256) void k_lengths(const unsigned char* mask, int* lengths){
  __shared__ int red[256];
  int b = blockIdx.x, t = threadIdx.x;
  unsigned char c0 = mask[0], c1 = mask[1];
  int mode;                     // 0=u8, 1=i32, 2=bf16/u16, 3=f32
  if (c0 == 0x80u) mode = 2;
  else if (c0 == 0u) mode = 3;
  else mode = (c1 != 0u) ? 0 : 1;
  int cnt = 0;
  for (int n = t; n < N_; n += 256){
    size_t idx = ((size_t)b*N_ + n)*N_ + n;
    int v;
    if (mode == 0)      v = (mask[idx] != 0);
    else if (mode == 1) v = (((const int*)mask)[idx] != 0);
    else if (mode == 2) v = (((const unsigned short*)mask)[idx] != 0);
    else                v = (((const float*)mask)[idx] != 0.0f);
    cnt += v;
  }
  red[t] = cnt; __syncthreads();
  for (int s = 128; s > 0; s >>= 1){ if (t < s) red[t] += red[t+s]; __syncthreads(); }
  if (t == 0) lengths[b] = red[0];
}

// ---------------- generic LayerNorm ----------------
// in_mode: >=0 -> flags[in_mode] decides; -1 -> f32 ws; -2 -> bf16 ws
__global__ __launch_bounds__(256) void k_ln(const void* in, const int* flags, int in_mode,
                                            const void* g, int gi, const void* bia, int bi,
                                            void* out, int out_bf16, int Clen){
  __shared__ float red[256];
  int fin = (in_mode >= 0) ? flags[in_mode] : (in_mode == -2 ? 1 : 0);
  int fg = flags[gi], fb = flags[bi];
  int row = blockIdx.x, t = threadIdx.x;
  size_t base = (size_t)row * Clen;
  float xs[3];
  int nv = (Clen + 255) >> 8;
  float s = 0.f;
  for (int i = 0; i < nv; i++){
    int c = t + (i << 8);
    float v = 0.f;
    if (c < Clen) v = ldf(in, base+c, fin);
    xs[i] = v; s += v;
  }
  red[t] = s; __syncthreads();
  for (int st = 128; st > 0; st >>= 1){ if (t < st) red[t] += red[t+st]; __syncthreads(); }
  float mean = red[0] / (float)Clen; __syncthreads();
  float s2 = 0.f;
  for (int i = 0; i < nv; i++){
    int c = t + (i << 8);
    if (c < Clen){ float d = xs[i] - mean; s2 += d*d; }
  }
  red[t] = s2; __syncthreads();
  for (int st = 128; st > 0; st >>= 1){ if (t < st) red[t] += red[t+st]; __syncthreads(); }
  float rstd = rsqrtf(red[0] / (float)Clen + EPS_);
  for (int i = 0; i < nv; i++){
    int c = t + (i << 8);
    if (c < Clen){
      float v = (xs[i]-mean)*rstd*ldf(g,c,fg) + ldf(bia,c,fb);
      if (out_bf16) ((bf16*)out)[base+c] = __float2bfloat16(v);
      else          ((float*)out)[base+c] = v;
    }
  }
}

// ---------------- tiled GEMMs (64x64 tile, K-chunk 16, 256 thr, 4x4/thr) ----------------
#define TM 64
#define TN 64
#define TK 16

// h(bf16 ws)[8192,256] @ Wqkv[256,768] + bqkv -> q/k/v bf16 ws [B,H,N,D]
__global__ __launch_bounds__(256) void k_qkv(const bf16* A, const void* Bw, const void* bias,
                                             const int* flags, bf16* qb, bf16* kb, bf16* vb){
  __shared__ float As[TK][TM+4];
  __shared__ float Bs[TK][TN];
  int fB = flags[3], fb = flags[4];
  int t = threadIdx.x, tx = t & 15, ty = t >> 4;
  int m0 = blockIdx.x * TM, n0 = blockIdx.y * TN;
  const int K = C_, Nw = 3*C_;
  float acc[4][4] = {};
  for (int k0 = 0; k0 < K; k0 += TK){
    #pragma unroll
    for (int s = 0; s < 4; s++){
      int flat = t + s*256; int j = flat & 15, i = flat >> 4;
      As[j][i] = b2f(A[(size_t)(m0+i)*K + k0 + j]);
    }
    #pragma unroll
    for (int s = 0; s < 4; s++){
      int flat = t + s*256; int j = flat & 63, i = flat >> 6;
      Bs[i][j] = ldf(Bw, (size_t)(k0+i)*Nw + n0 + j, fB);
    }
    __syncthreads();
    #pragma unroll
    for (int k = 0; k < TK; k++){
      float4 a4 = *(const float4*)&As[k][ty*4];
      float4 b4 = *(const float4*)&Bs[k][tx*4];
      float av[4] = {a4.x,a4.y,a4.z,a4.w};
      float bv[4] = {b4.x,b4.y,b4.z,b4.w};
      #pragma unroll
      for (int i = 0; i < 4; i++)
        #pragma unroll
        for (int j = 0; j < 4; j++) acc[i][j] += av[i]*bv[j];
    }
    __syncthreads();
  }
  #pragma unroll
  for (int i = 0; i < 4; i++){
    int m = m0 + ty*4 + i;
    int bb = m >> 10, nn = m & 1023;
    #pragma unroll
    for (int j = 0; j < 4; j++){
      int n = n0 + tx*4 + j;
      float c = acc[i][j] + ldf(bias, n, fb);
      int three = n >> 8, hh = (n >> 5) & 7, d = n & 31;
      bf16* dst = (three == 0) ? qb : ((three == 1) ? kb : vb);
      dst[(((size_t)bb*H_ + hh)*N_ + nn)*D_ + d] = __float2bfloat16(c);
    }
  }
}

// ao(f32 ws)[8192,256] @ Wout + bout ; x = inputs + gamma1*(.) -> xbuf f32 ws
__global__ __launch_bounds__(256) void k_outproj(const float* A, const void* Bw, const void* bias,
                                                 const void* inputs, const void* gamma1,
                                                 const int* flags, float* xout){
  __shared__ float As[TK][TM+4];
  __shared__ float Bs[TK][TN];
  int fB = flags[9], fb = flags[10], fin = flags[0], fg = flags[15];
  int t = threadIdx.x, tx = t & 15, ty = t >> 4;
  int m0 = blockIdx.x * TM, n0 = blockIdx.y * TN;
  const int K = C_, Nw = C_;
  float acc[4][4] = {};
  for (int k0 = 0; k0 < K; k0 += TK){
    #pragma unroll
    for (int s = 0; s < 4; s++){
      int flat = t + s*256; int j = flat & 15, i = flat >> 4;
      As[j][i] = A[(size_t)(m0+i)*K + k0 + j];
    }
    #pragma unroll
    for (int s = 0; s < 4; s++){
      int flat = t + s*256; int j = flat & 63, i = flat >> 6;
      Bs[i][j] = ldf(Bw, (size_t)(k0+i)*Nw + n0 + j, fB);
    }
    __syncthreads();
    #pragma unroll
    for (int k = 0; k < TK; k++){
      float4 a4 = *(const float4*)&As[k][ty*4];
      float4 b4 = *(const float4*)&Bs[k][tx*4];
      float av[4] = {a4.x,a4.y,a4.z,a4.w};
      float bv[4] = {b4.x,b4.y,b4.z,b4.w};
      #pragma unroll
      for (int i = 0; i < 4; i++)
        #pragma unroll
        for (int j = 0; j < 4; j++) acc[i][j] += av[i]*bv[j];
    }
    __syncthreads();
  }
  #pragma unroll
  for (int i = 0; i < 4; i++){
    int m = m0 + ty*4 + i;
    #pragma unroll
    for (int j = 0; j < 4; j++){
      int n = n0 + tx*4 + j;
      float c = acc[i][j] + ldf(bias, n, fb);
      size_t idx = (size_t)m*C_ + n;
      xout[idx] = ldf(inputs, idx, fin) + ldf(gamma1, n, fg) * c;
    }
  }
}

__device__ __forceinline__ float gelu_exact(float x){
  return 0.5f * x * (1.0f + erff(x * 0.70710678118654752f));
}

// h2(bf16 ws)[8192,256] @ {W_wide,W_gate}[256,682] ; f = gelu(a)*b -> fbuf bf16 ws
__global__ __launch_bounds__(256) void k_ffn1(const bf16* A, const void* Ww, const void* Wg,
                                              const int* flags, bf16* fout){
  __shared__ float As[TK][TM+4];
  __shared__ float Bs[TK][TN];
  __shared__ float Cs[TK][TN];
  int fw = flags[17], fg = flags[18];
  int t = threadIdx.x, tx = t & 15, ty = t >> 4;
  int m0 = blockIdx.x * TM, n0 = blockIdx.y * TN;
  const int K = C_, Nw = F_;
  float acc1[4][4] = {}, acc2[4][4] = {};
  for (int k0 = 0; k0 < K; k0 += TK){
    #pragma unroll
    for (int s = 0; s < 4; s++){
      int flat = t + s*256; int j = flat & 15, i = flat >> 4;
      As[j][i] = b2f(A[(size_t)(m0+i)*K + k0 + j]);
    }
    #pragma unroll
    for (int s = 0; s < 4; s++){
      int flat = t + s*256; int j = flat & 63, i = flat >> 6;
      int n = n0 + j;
      float bw = 0.f, bg = 0.f;
      if (n < Nw){
        bw = ldf(Ww, (size_t)(k0+i)*Nw + n, fw);
        bg = ldf(Wg, (size_t)(k0+i)*Nw + n, fg);
      }
      Bs[i][j] = bw; Cs[i][j] = bg;
    }
    __syncthreads();
    #pragma unroll
    for (int k = 0; k < TK; k++){
      float4 a4 = *(const float4*)&As[k][ty*4];
      float4 b4 = *(const float4*)&Bs[k][tx*4];
      float4 c4 = *(const float4*)&Cs[k][tx*4];
      float av[4] = {a4.x,a4.y,a4.z,a4.w};
      float bv[4] = {b4.x,b4.y,b4.z,b4.w};
      float cv[4] = {c4.x,c4.y,c4.z,c4.w};
      #pragma unroll
      for (int i = 0; i < 4; i++)
        #pragma unroll
        for (int j = 0; j < 4; j++){ acc1[i][j] += av[i]*bv[j]; acc2[i][j] += av[i]*cv[j]; }
    }
    __syncthreads();
  }
  #pragma unroll
  for (int i = 0; i < 4; i++){
    int m = m0 + ty*4 + i;
    #pragma unroll
    for (int j = 0; j < 4; j++){
      int n = n0 + tx*4 + j;
      if (n < Nw) fout[(size_t)m*F_ + n] = __float2bfloat16(gelu_exact(acc1[i][j]) * acc2[i][j]);
    }
  }
}

// f(bf16 ws)[8192,682] @ W_down[682,256] ; out = x + gamma2*(.) -> d_out (dtype = flags[0])
__global__ __launch_bounds__(256) void k_down(const bf16* A, const void* Bw, const float* xbuf,
                                              const void* gamma2, const int* flags, void* out){
  __shared__ float As[TK][TM+4];
  __shared__ float Bs[TK][TN];
  int fB = flags[19], fg = flags[16], fo = flags[0];
  int t = threadIdx.x, tx = t & 15, ty = t >> 4;
  int m0 = blockIdx.x * TM, n0 = blockIdx.y * TN;
  const int K = F_, Nw = C_;
  float acc[4][4] = {};
  for (int k0 = 0; k0 < K; k0 += TK){
    #pragma unroll
    for (int s = 0; s < 4; s++){
      int flat = t + s*256; int j = flat & 15, i = flat >> 4;
      As[j][i] = (k0 + j < K) ? b2f(A[(size_t)(m0+i)*K + k0 + j]) : 0.f;
    }
    #pragma unroll
    for (int s = 0; s < 4; s++){
      int flat = t + s*256; int j = flat & 63, i = flat >> 6;
      Bs[i][j] = (k0 + i < K) ? ldf(Bw, (size_t)(k0+i)*Nw + n0 + j, fB) : 0.f;
    }
    __syncthreads();
    #pragma unroll
    for (int k = 0; k < TK; k++){
      float4 a4 = *(const float4*)&As[k][ty*4];
      float4 b4 = *(const float4*)&Bs[k][tx*4];
      float av[4] = {a4.x,a4.y,a4.z,a4.w};
      float bv[4] = {b4.x,b4.y,b4.z,b4.w};
      #pragma unroll
      for (int i = 0; i < 4; i++)
        #pragma unroll
        for (int j = 0; j < 4; j++) acc[i][j] += av[i]*bv[j];
    }
    __syncthreads();
  }
  #pragma unroll
  for (int i = 0; i < 4; i++){
    int m = m0 + ty*4 + i;
    #pragma unroll
    for (int j = 0; j < 4; j++){
      int n = n0 + tx*4 + j;
      size_t idx = (size_t)m*C_ + n;
      float val = xbuf[idx] + ldf(gamma2, n, fg) * acc[i][j];
      if (fo) ((bf16*)out)[idx] = __float2bfloat16(val);
      else    ((float*)out)[idx] = val;
    }
  }
}

// ---------------- attention pass A: per-(b,g,n) masked softmax stats (M, L) ----------------
__global__ __launch_bounds__(256) void k_stats(const bf16* qb, const bf16* kb,
                                               const void* Wt1, const void* bt1, const void* inter,
                                               const int* flags, const int* lengths, float2* stats){
  __shared__ float qs[16][260];
  __shared__ float ks[16][260];
  __shared__ float sc[8][16][17];
  __shared__ float w1[64], b1s[8];
  int fw1 = flags[5], fb1 = flags[6], fint = flags[2];
  int t = threadIdx.x;
  int ntile = blockIdx.x, b = blockIdx.y;
  int n0 = ntile * 16;
  int len = lengths[b];
  if (t < 64) w1[t] = ldf(Wt1, t, fw1);
  if (t < 8)  b1s[t] = ldf(bt1, t, fb1);
  #pragma unroll
  for (int s = 0; s < 16; s++){
    int flat = t + s*256;
    int ri = flat >> 8, c = flat & 255;
    int hh = c >> 5, d = c & 31;
    qs[ri][c] = b2f(qb[(((size_t)b*H_ + hh)*N_ + (n0+ri))*D_ + d]);
  }
  int mi = t & 15, ni = t >> 4;
  float M = -3.0e38f, L = 0.f;
  for (int mt = 0; mt < 64; mt++){
    int m0 = mt * 16;
    __syncthreads();
    #pragma unroll
    for (int s = 0; s < 16; s++){
      int flat = t + s*256;
      int ri = flat >> 8, c = flat & 255;
      int hh = c >> 5, d = c & 31;
      ks[ri][c] = b2f(kb[(((size_t)b*H_ + hh)*N_ + (m0+ri))*D_ + d]);
    }
    __syncthreads();
    float acch[8];
    #pragma unroll
    for (int h = 0; h < 8; h++){
      const float* qrow = &qs[ni][h*32];
      const float* krow = &ks[mi][h*32];
      float a = 0.f;
      #pragma unroll
      for (int dv = 0; dv < 8; dv++){
        float4 q4 = *(const float4*)(qrow + dv*4);
        float4 k4 = *(const float4*)(krow + dv*4);
        a += q4.x*k4.x + q4.y*k4.y + q4.z*k4.z + q4.w*k4.w;
      }
      acch[h] = a * 0.17677669529663687f;
    }
    size_t ibase = (((size_t)b*N_ + (n0+ni))*N_ + (m0+mi)) * H_;
    float ifl[8];
    #pragma unroll
    for (int g = 0; g < 8; g++) ifl[g] = ldf(inter, ibase + g, fint);
    #pragma unroll
    for (int g = 0; g < 8; g++){
      float v = b1s[g] + ifl[g];
      #pragma unroll
      for (int h = 0; h < 8; h++) v += acch[h] * w1[h*8 + g];
      sc[g][ni][mi] = v;
    }
    __syncthreads();
    if (t < 128){
      int g = t >> 4, nn = t & 15;
      int n = n0 + nn;
      float tmax = -3.0e38f;
      #pragma unroll
      for (int j = 0; j < 16; j++){
        int m = m0 + j;
        bool ok = (n >= len) || (m < len);
        float v = ok ? sc[g][nn][j] : -3.0e38f;
        tmax = fmaxf(tmax, v);
      }
      if (tmax > -1.0e38f){
        float Mn = fmaxf(M, tmax);
        L *= __expf(M - Mn);
        #pragma unroll
        for (int j = 0; j < 16; j++){
          int m = m0 + j;
          bool ok = (n >= len) || (m < len);
          if (ok) L += __expf(sc[g][nn][j] - Mn);
        }
        M = Mn;
      }
    }
  }
  if (t < 128){
    int g = t >> 4, nn = t & 15;
    stats[((size_t)b*H_ + g)*N_ + n0 + nn] = make_float2(M, L);
  }
}

// ---------------- attention pass B: recompute scores, normalize, th2-mix, PV ----------------
__global__ __launch_bounds__(256) void k_attn(const bf16* qb, const bf16* kb, const bf16* vb,
                                              const void* Wt1, const void* bt1,
                                              const void* Wt2, const void* bt2,
                                              const void* inter, const int* flags,
                                              const int* lengths, const float2* stats, float* aobuf){
  __shared__ float qs[16][260];
  __shared__ float ks[16][260];
  __shared__ float vs[16][260];
  __shared__ float ald[8][16][17];
  __shared__ float w1[64], w2[64], b1s[8], b2s[8];
  __shared__ float Ms[8][16], Li[8][16];
  int fw1 = flags[5], fb1 = flags[6], fw2 = flags[7], fb2 = flags[8], fint = flags[2];
  int t = threadIdx.x;
  int ntile = blockIdx.x, b = blockIdx.y;
  int n0 = ntile * 16;
  int len = lengths[b];
  if (t < 64){ w1[t] = ldf(Wt1, t, fw1); w2[t] = ldf(Wt2, t, fw2); }
  if (t < 8){ b1s[t] = ldf(bt1, t, fb1); b2s[t] = ldf(bt2, t, fb2); }
  if (t < 128){
    int g = t >> 4, nn = t & 15;
    float2 st = stats[((size_t)b*H_ + g)*N_ + n0 + nn];
    Ms[g][nn] = st.x;
    Li[g][nn] = 1.0f / st.y;
  }
  #pragma unroll
  for (int s = 0; s < 16; s++){
    int flat = t + s*256;
    int ri = flat >> 8, c = flat & 255;
    int hh = c >> 5, d = c & 31;
    qs[ri][c] = b2f(qb[(((size_t)b*H_ + hh)*N_ + (n0+ri))*D_ + d]);
  }
  int mi = t & 15, ni = t >> 4;
  int g2 = t >> 5, rem = t & 31, nn2 = rem >> 1, half = rem & 1;
  float acc[16] = {};
  float sv[16] = {};
  for (int mt = 0; mt < 64; mt++){
    int m0 = mt * 16;
    __syncthreads();
    #pragma unroll
    for (int s = 0; s < 32; s++){
      int flat = t + s*256;
      int sel = flat >> 12;             // 0 = ks, 1 = vs
      int ri = (flat >> 8) & 15, c = flat & 255;
      int hh = c >> 5, d = c & 31;
      size_t gidx = (((size_t)b*H_ + hh)*N_ + (m0+ri))*D_ + d;
      float val = sel ? b2f(vb[gidx]) : b2f(kb[gidx]);
      if (sel) vs[ri][c] = val; else ks[ri][c] = val;
    }
    __syncthreads();
    {
      float acch[8];
      #pragma unroll
      for (int h = 0; h < 8; h++){
        const float* qrow = &qs[ni][h*32];
        const float* krow = &ks[mi][h*32];
        float a = 0.f;
        #pragma unroll
        for (int dv = 0; dv < 8; dv++){
          float4 q4 = *(const float4*)(qrow + dv*4);
          float4 k4 = *(const float4*)(krow + dv*4);
          a += q4.x*k4.x + q4.y*k4.y + q4.z*k4.z + q4.w*k4.w;
        }
        acch[h] = a * 0.17677669529663687f;
      }
      size_t ibase = (((size_t)b*N_ + (n0+ni))*N_ + (m0+mi)) * H_;
      float ifl[8];
      #pragma unroll
      for (int g = 0; g < 8; g++) ifl[g] = ldf(inter, ibase + g, fint);
      int n = n0 + ni, m = m0 + mi;
      bool ok = (n >= len) || (m < len);
      float p[8];
      #pragma unroll
      for (int g = 0; g < 8; g++){
        float v = b1s[g] + ifl[g];
        #pragma unroll
        for (int h = 0; h < 8; h++) v += acch[h] * w1[h*8 + g];
        p[g] = ok ? __expf(v - Ms[g][ni]) * Li[g][ni] : 0.f;
      }
      #pragma unroll
      for (int gg = 0; gg < 8; gg++){
        float a2 = 0.f;
        #pragma unroll
        for (int g = 0; g < 8; g++) a2 += p[g] * w2[g*8 + gg];
        ald[gg][ni][mi] = a2;
      }
    }
    __syncthreads();
    #pragma unroll
    for (int mm = 0; mm < 16; mm++){
      float a2v = ald[g2][nn2][mm];
      const float* vrow = &vs[mm][g2*32 + half*16];
      #pragma unroll
      for (int j = 0; j < 16; j++){
        float vv = vrow[j];
        acc[j] += a2v * vv;
        sv[j]  += vv;
      }
    }
  }
  float btg = b2s[g2];
  size_t obase = ((size_t)b*N_ + (n0+nn2))*C_ + g2*D_ + half*16;
  #pragma unroll
  for (int j = 0; j < 16; j++) aobuf[obase + j] = acc[j] + btg * sv[j];
}

// ---------------- launcher ----------------
extern "C" void kernel_launch(void* const* d_in, const int* in_sizes, int n_in,
                              void* d_out, int out_size, void* d_ws, size_t ws_size,
                              hipStream_t stream) {
  Ptrs ptrs;
  for (int i = 0; i < 22; i++) ptrs.p[i] = d_in[i];
  const unsigned char* mask = (const unsigned char*)d_in[1];

  // workspace layout (~45 MB total)
  char* ws = (char*)d_ws;
  size_t o = 0;
  size_t o_flags = o; o += 256;
  size_t o_len   = o; o += 256;
  size_t o_stats = o; o += (size_t)B_*H_*N_*sizeof(float2);   // 512 KB
  size_t o_h     = o; o += (size_t)B_*N_*C_*2;                // 4 MB  bf16
  size_t o_q     = o; o += (size_t)B_*N_*C_*2;
  size_t o_k     = o; o += (size_t)B_*N_*C_*2;
  size_t o_v     = o; o += (size_t)B_*N_*C_*2;
  size_t o_ao    = o; o += (size_t)B_*N_*C_*4;                // 8 MB  f32
  size_t o_x     = o; o += (size_t)B_*N_*C_*4;                // 8 MB  f32
  size_t o_f     = o; o += (size_t)B_*N_*F_*2;                // 11 MB bf16

  int*    flags   = (int*)(ws + o_flags);
  int*    lengths = (int*)(ws + o_len);
  float2* stats   = (float2*)(ws + o_stats);
  bf16*   hbuf    = (bf16*)(ws + o_h);
  bf16*   qbuf    = (bf16*)(ws + o_q);
  bf16*   kbuf    = (bf16*)(ws + o_k);
  bf16*   vbuf    = (bf16*)(ws + o_v);
  float*  aobuf   = (float*)(ws + o_ao);
  float*  xbuf    = (float*)(ws + o_x);
  bf16*   fbuf    = (bf16*)(ws + o_f);

  k_sniff<<<1, 64, 0, stream>>>(ptrs, flags);
  k_lengths<<<8, 256, 0, stream>>>(mask, lengths);
  k_ln<<<B_*N_, 256, 0, stream>>>(d_in[0], flags, 0, d_in[11], 11, d_in[12], 12, hbuf, 1, C_);
  k_qkv<<<dim3(128, 12), 256, 0, stream>>>(hbuf, d_in[3], d_in[4], flags, qbuf, kbuf, vbuf);
  k_stats<<<dim3(64, 8), 256, 0, stream>>>(qbuf, kbuf, d_in[5], d_in[6], d_in[2], flags, lengths, stats);
  k_attn<<<dim3(64, 8), 256, 0, stream>>>(qbuf, kbuf, vbuf, d_in[5], d_in[6], d_in[7], d_in[8],
                                          d_in[2], flags, lengths, stats, aobuf);
  k_outproj<<<dim3(128, 4), 256, 0, stream>>>(aobuf, d_in[9], d_in[10], d_in[0], d_in[15], flags, xbuf);
  k_ln<<<B_*N_, 256, 0, stream>>>(xbuf, flags, -1, d_in[13], 13, d_in[14], 14, hbuf, 1, C_);
  k_ffn1<<<dim3(128, 11), 256, 0, stream>>>(hbuf, d_in[17], d_in[18], flags, fbuf);
  k_ln<<<B_*N_, 256, 0, stream>>>(fbuf, flags, -2, d_in[20], 20, d_in[21], 21, fbuf, 1, F_);
  k_down<<<dim3(128, 4), 256, 0, stream>>>(fbuf, d_in[19], xbuf, d_in[16], flags, d_out);
}

// Round 4
// 1299.546 us; speedup vs baseline: 2.6683x; 2.6683x over previous
//
#include <hip/hip_runtime.h>
#include <hip/hip_bf16.h>
#include <math.h>

#define B_ 8
#define N_ 1024
#define C_ 256
#define H_ 8
#define D_ 32
#define F_ 682
#define EPS_ 1e-3f

typedef const __hip_bfloat16* bf16cp;
typedef __hip_bfloat16 bf16;
typedef __attribute__((ext_vector_type(8))) short short8;
typedef __attribute__((ext_vector_type(4))) float f32x4;

__device__ __forceinline__ float b2f(bf16 v){ return __bfloat162float(v); }
__device__ __forceinline__ float us2f(unsigned int u){ return __uint_as_float(u << 16); }
__device__ __forceinline__ unsigned short f2bu(float f){   // f32 -> bf16 bits, RNE
  unsigned int u = __float_as_uint(f);
  return (unsigned short)((u + 0x7FFFu + ((u >> 16) & 1u)) >> 16);
}

// flag-aware load: bf=1 -> bf16, bf=0 -> f32
__device__ __forceinline__ float ldf(const void* p, size_t i, int bf){
  return bf ? b2f(((bf16cp)p)[i]) : ((const float*)p)[i];
}

struct Ptrs { const void* p[22]; };

// ---------------- per-tensor dtype sniffer ----------------
__global__ void k_sniff(Ptrs ptrs, int* flags){
  if (threadIdx.x != 0 || blockIdx.x != 0) return;
  const int sizes[22] = {2097152, 8388608, 8388608, 196608, 768, 64, 8, 64, 8,
                         65536, 256, 256, 256, 256, 256, 256, 256,
                         174592, 174592, 174592, 682, 682};
  for (int i = 0; i < 22; i++){
    if (i == 1){ flags[i] = 0; continue; }
    const unsigned short* u = (const unsigned short*)ptrs.p[i];
    int nu = sizes[i] < 64 ? sizes[i] : 64;
    int badB = 0, badF = 0, evenAllZero = 1, oddAny = 0;
    for (int j = 0; j < nu; j++){
      unsigned short x = u[j];
      float vb = us2f((unsigned int)x);
      float ab = fabsf(vb);
      if (!(vb == 0.0f) && (!(ab <= 1e3f) || ab < 1e-30f || vb != vb)) badB++;
      if ((j & 1) == 0){ if (x) evenAllZero = 0; }
      else            { if (x) oddAny = 1; }
    }
    for (int j = 0; j + 1 < nu; j += 2){
      unsigned int w = ((unsigned int)u[j]) | (((unsigned int)u[j+1]) << 16);
      float vf = __uint_as_float(w);
      float af = fabsf(vf);
      if (!(vf == 0.0f) && (!(af <= 1e3f) || af < 1e-30f || vf != vf)) badF++;
    }
    int bf;
    if (badB > badF) bf = 0;
    else if (badF > badB) bf = 1;
    else bf = (evenAllZero && oddAny) ? 0 : 1;
    flags[i] = bf;
  }
}

// ---------------- lengths from mask diagonal ----------------
__global__ __launch_bounds__(256) void k_lengths(const unsigned char* mask, int* lengths){
  __shared__ int red[256];
  int b = blockIdx.x, t = threadIdx.x;
  unsigned char c0 = mask[0], c1 = mask[1];
  int mode;
  if (c0 == 0x80u) mode = 2;
  else if (c0 == 0u) mode = 3;
  else mode = (c1 != 0u) ? 0 : 1;
  int cnt = 0;
  for (int n = t; n < N_; n += 256){
    size_t idx = ((size_t)b*N_ + n)*N_ + n;
    int v;
    if (mode == 0)      v = (mask[idx] != 0);
    else if (mode == 1) v = (((const int*)mask)[idx] != 0);
    else if (mode == 2) v = (((const unsigned short*)mask)[idx] != 0);
    else                v = (((const float*)mask)[idx] != 0.0f);
    cnt += v;
  }
  red[t] = cnt; __syncthreads();
  for (int s = 128; s > 0; s >>= 1){ if (t < s) red[t] += red[t+s]; __syncthreads(); }
  if (t == 0) lengths[b] = red[0];
}

// ---------------- generic LayerNorm ----------------
__global__ __launch_bounds__(256) void k_ln(const void* in, const int* flags, int in_mode,
                                            const void* g, int gi, const void* bia, int bi,
                                            void* out, int out_bf16, int Clen){
  __shared__ float red[256];
  int fin = (in_mode >= 0) ? flags[in_mode] : (in_mode == -2 ? 1 : 0);
  int fg = flags[gi], fb = flags[bi];
  int row = blockIdx.x, t = threadIdx.x;
  size_t base = (size_t)row * Clen;
  float xs[3];
  int nv = (Clen + 255) >> 8;
  float s = 0.f;
  for (int i = 0; i < nv; i++){
    int c = t + (i << 8);
    float v = 0.f;
    if (c < Clen) v = ldf(in, base+c, fin);
    xs[i] = v; s += v;
  }
  red[t] = s; __syncthreads();
  for (int st = 128; st > 0; st >>= 1){ if (t < st) red[t] += red[t+st]; __syncthreads(); }
  float mean = red[0] / (float)Clen; __syncthreads();
  float s2 = 0.f;
  for (int i = 0; i < nv; i++){
    int c = t + (i << 8);
    if (c < Clen){ float d = xs[i] - mean; s2 += d*d; }
  }
  red[t] = s2; __syncthreads();
  for (int st = 128; st > 0; st >>= 1){ if (t < st) red[t] += red[t+st]; __syncthreads(); }
  float rstd = rsqrtf(red[0] / (float)Clen + EPS_);
  for (int i = 0; i < nv; i++){
    int c = t + (i << 8);
    if (c < Clen){
      float v = (xs[i]-mean)*rstd*ldf(g,c,fg) + ldf(bia,c,fb);
      if (out_bf16) ((bf16*)out)[base+c] = __float2bfloat16(v);
      else          ((float*)out)[base+c] = v;
    }
  }
}

// ---------------- scalar tiled GEMMs (unchanged this round) ----------------
#define TM 64
#define TN 64
#define TK 16

__global__ __launch_bounds__(256) void k_qkv(const bf16* A, const void* Bw, const void* bias,
                                             const int* flags, bf16* qb, bf16* kb, bf16* vb){
  __shared__ float As[TK][TM+4];
  __shared__ float Bs[TK][TN];
  int fB = flags[3], fb = flags[4];
  int t = threadIdx.x, tx = t & 15, ty = t >> 4;
  int m0 = blockIdx.x * TM, n0 = blockIdx.y * TN;
  const int K = C_, Nw = 3*C_;
  float acc[4][4] = {};
  for (int k0 = 0; k0 < K; k0 += TK){
    #pragma unroll
    for (int s = 0; s < 4; s++){
      int flat = t + s*256; int j = flat & 15, i = flat >> 4;
      As[j][i] = b2f(A[(size_t)(m0+i)*K + k0 + j]);
    }
    #pragma unroll
    for (int s = 0; s < 4; s++){
      int flat = t + s*256; int j = flat & 63, i = flat >> 6;
      Bs[i][j] = ldf(Bw, (size_t)(k0+i)*Nw + n0 + j, fB);
    }
    __syncthreads();
    #pragma unroll
    for (int k = 0; k < TK; k++){
      float4 a4 = *(const float4*)&As[k][ty*4];
      float4 b4 = *(const float4*)&Bs[k][tx*4];
      float av[4] = {a4.x,a4.y,a4.z,a4.w};
      float bv[4] = {b4.x,b4.y,b4.z,b4.w};
      #pragma unroll
      for (int i = 0; i < 4; i++)
        #pragma unroll
        for (int j = 0; j < 4; j++) acc[i][j] += av[i]*bv[j];
    }
    __syncthreads();
  }
  #pragma unroll
  for (int i = 0; i < 4; i++){
    int m = m0 + ty*4 + i;
    int bb = m >> 10, nn = m & 1023;
    #pragma unroll
    for (int j = 0; j < 4; j++){
      int n = n0 + tx*4 + j;
      float c = acc[i][j] + ldf(bias, n, fb);
      int three = n >> 8, hh = (n >> 5) & 7, d = n & 31;
      bf16* dst = (three == 0) ? qb : ((three == 1) ? kb : vb);
      dst[(((size_t)bb*H_ + hh)*N_ + nn)*D_ + d] = __float2bfloat16(c);
    }
  }
}

__global__ __launch_bounds__(256) void k_outproj(const float* A, const void* Bw, const void* bias,
                                                 const void* inputs, const void* gamma1,
                                                 const int* flags, float* xout){
  __shared__ float As[TK][TM+4];
  __shared__ float Bs[TK][TN];
  int fB = flags[9], fb = flags[10], fin = flags[0], fg = flags[15];
  int t = threadIdx.x, tx = t & 15, ty = t >> 4;
  int m0 = blockIdx.x * TM, n0 = blockIdx.y * TN;
  const int K = C_, Nw = C_;
  float acc[4][4] = {};
  for (int k0 = 0; k0 < K; k0 += TK){
    #pragma unroll
    for (int s = 0; s < 4; s++){
      int flat = t + s*256; int j = flat & 15, i = flat >> 4;
      As[j][i] = A[(size_t)(m0+i)*K + k0 + j];
    }
    #pragma unroll
    for (int s = 0; s < 4; s++){
      int flat = t + s*256; int j = flat & 63, i = flat >> 6;
      Bs[i][j] = ldf(Bw, (size_t)(k0+i)*Nw + n0 + j, fB);
    }
    __syncthreads();
    #pragma unroll
    for (int k = 0; k < TK; k++){
      float4 a4 = *(const float4*)&As[k][ty*4];
      float4 b4 = *(const float4*)&Bs[k][tx*4];
      float av[4] = {a4.x,a4.y,a4.z,a4.w};
      float bv[4] = {b4.x,b4.y,b4.z,b4.w};
      #pragma unroll
      for (int i = 0; i < 4; i++)
        #pragma unroll
        for (int j = 0; j < 4; j++) acc[i][j] += av[i]*bv[j];
    }
    __syncthreads();
  }
  #pragma unroll
  for (int i = 0; i < 4; i++){
    int m = m0 + ty*4 + i;
    #pragma unroll
    for (int j = 0; j < 4; j++){
      int n = n0 + tx*4 + j;
      float c = acc[i][j] + ldf(bias, n, fb);
      size_t idx = (size_t)m*C_ + n;
      xout[idx] = ldf(inputs, idx, fin) + ldf(gamma1, n, fg) * c;
    }
  }
}

__device__ __forceinline__ float gelu_exact(float x){
  return 0.5f * x * (1.0f + erff(x * 0.70710678118654752f));
}

__global__ __launch_bounds__(256) void k_ffn1(const bf16* A, const void* Ww, const void* Wg,
                                              const int* flags, bf16* fout){
  __shared__ float As[TK][TM+4];
  __shared__ float Bs[TK][TN];
  __shared__ float Cs[TK][TN];
  int fw = flags[17], fg = flags[18];
  int t = threadIdx.x, tx = t & 15, ty = t >> 4;
  int m0 = blockIdx.x * TM, n0 = blockIdx.y * TN;
  const int K = C_, Nw = F_;
  float acc1[4][4] = {}, acc2[4][4] = {};
  for (int k0 = 0; k0 < K; k0 += TK){
    #pragma unroll
    for (int s = 0; s < 4; s++){
      int flat = t + s*256; int j = flat & 15, i = flat >> 4;
      As[j][i] = b2f(A[(size_t)(m0+i)*K + k0 + j]);
    }
    #pragma unroll
    for (int s = 0; s < 4; s++){
      int flat = t + s*256; int j = flat & 63, i = flat >> 6;
      int n = n0 + j;
      float bw = 0.f, bg = 0.f;
      if (n < Nw){
        bw = ldf(Ww, (size_t)(k0+i)*Nw + n, fw);
        bg = ldf(Wg, (size_t)(k0+i)*Nw + n, fg);
      }
      Bs[i][j] = bw; Cs[i][j] = bg;
    }
    __syncthreads();
    #pragma unroll
    for (int k = 0; k < TK; k++){
      float4 a4 = *(const float4*)&As[k][ty*4];
      float4 b4 = *(const float4*)&Bs[k][tx*4];
      float4 c4 = *(const float4*)&Cs[k][tx*4];
      float av[4] = {a4.x,a4.y,a4.z,a4.w};
      float bv[4] = {b4.x,b4.y,b4.z,b4.w};
      float cv[4] = {c4.x,c4.y,c4.z,c4.w};
      #pragma unroll
      for (int i = 0; i < 4; i++)
        #pragma unroll
        for (int j = 0; j < 4; j++){ acc1[i][j] += av[i]*bv[j]; acc2[i][j] += av[i]*cv[j]; }
    }
    __syncthreads();
  }
  #pragma unroll
  for (int i = 0; i < 4; i++){
    int m = m0 + ty*4 + i;
    #pragma unroll
    for (int j = 0; j < 4; j++){
      int n = n0 + tx*4 + j;
      if (n < Nw) fout[(size_t)m*F_ + n] = __float2bfloat16(gelu_exact(acc1[i][j]) * acc2[i][j]);
    }
  }
}

__global__ __launch_bounds__(256) void k_down(const bf16* A, const void* Bw, const float* xbuf,
                                              const void* gamma2, const int* flags, void* out){
  __shared__ float As[TK][TM+4];
  __shared__ float Bs[TK][TN];
  int fB = flags[19], fg = flags[16], fo = flags[0];
  int t = threadIdx.x, tx = t & 15, ty = t >> 4;
  int m0 = blockIdx.x * TM, n0 = blockIdx.y * TN;
  const int K = F_, Nw = C_;
  float acc[4][4] = {};
  for (int k0 = 0; k0 < K; k0 += TK){
    #pragma unroll
    for (int s = 0; s < 4; s++){
      int flat = t + s*256; int j = flat & 15, i = flat >> 4;
      As[j][i] = (k0 + j < K) ? b2f(A[(size_t)(m0+i)*K + k0 + j]) : 0.f;
    }
    #pragma unroll
    for (int s = 0; s < 4; s++){
      int flat = t + s*256; int j = flat & 63, i = flat >> 6;
      Bs[i][j] = (k0 + i < K) ? ldf(Bw, (size_t)(k0+i)*Nw + n0 + j, fB) : 0.f;
    }
    __syncthreads();
    #pragma unroll
    for (int k = 0; k < TK; k++){
      float4 a4 = *(const float4*)&As[k][ty*4];
      float4 b4 = *(const float4*)&Bs[k][tx*4];
      float av[4] = {a4.x,a4.y,a4.z,a4.w};
      float bv[4] = {b4.x,b4.y,b4.z,b4.w};
      #pragma unroll
      for (int i = 0; i < 4; i++)
        #pragma unroll
        for (int j = 0; j < 4; j++) acc[i][j] += av[i]*bv[j];
    }
    __syncthreads();
  }
  #pragma unroll
  for (int i = 0; i < 4; i++){
    int m = m0 + ty*4 + i;
    #pragma unroll
    for (int j = 0; j < 4; j++){
      int n = n0 + tx*4 + j;
      size_t idx = (size_t)m*C_ + n;
      float val = xbuf[idx] + ldf(gamma2, n, fg) * acc[i][j];
      if (fo) ((bf16*)out)[idx] = __float2bfloat16(val);
      else    ((float*)out)[idx] = val;
    }
  }
}

// ---------------- Vsum[b][g][d] = sum_m V ----------------
__global__ __launch_bounds__(256) void k_vsum(const bf16* vb, float* vsum){
  __shared__ float red[8][32];
  int bg = blockIdx.x;            // b*8+g
  int t = threadIdx.x;
  int d = t & 31, mg = t >> 5;
  float s = 0.f;
  for (int m = mg*128; m < mg*128 + 128; m++)
    s += b2f(vb[((size_t)bg*N_ + m)*D_ + d]);
  red[mg][d] = s; __syncthreads();
  if (t < 32){
    float a = 0.f;
    #pragma unroll
    for (int i = 0; i < 8; i++) a += red[i][t];
    vsum[(size_t)bg*D_ + t] = a;
  }
}

// ============ MFMA attention pass A: softmax stats (M, L) per (b,g,n) ============
// transposed S (a=K, b=Q): C col = n = lane&15, row = m = quad*4+reg
__global__ __launch_bounds__(256) void k_stats2(const bf16* qb, const bf16* kb,
                                                const void* Wt1, const void* bt1, const void* inter,
                                                const int* flags, const int* lengths, float2* stats){
  __shared__ float w1s[64], b1v[8];
  __shared__ float swM[4][8][16], swL[4][8][16];
  int fw1 = flags[5], fb1 = flags[6], fint = flags[2];
  int t = threadIdx.x;
  int ntile = blockIdx.x, b = blockIdx.y;
  int n0 = ntile * 16;
  int len = lengths[b];
  if (t < 64) w1s[t] = ldf(Wt1, t, fw1) * 0.17677669529663687f;  // fold 1/sqrt(32)
  if (t < 8)  b1v[t] = ldf(bt1, t, fb1);
  __syncthreads();
  int lane = t & 63, w = t >> 6;
  int c = lane & 15, q = lane >> 4;
  const unsigned short* qus = (const unsigned short*)qb;
  const unsigned short* kus = (const unsigned short*)kb;
  short8 qfrag[8];
  #pragma unroll
  for (int h = 0; h < 8; h++)
    qfrag[h] = *(const short8*)(qus + (((size_t)b*8 + h)*N_ + n0 + c)*D_ + q*8);
  int n_g = n0 + c;
  float M[8], L[8];
  #pragma unroll
  for (int g = 0; g < 8; g++){ M[g] = -1e30f; L[g] = 0.f; }

  for (int ci = 0; ci < 8; ci++){
    int m0c = w*256 + ci*32;
    #pragma unroll
    for (int mt = 0; mt < 2; mt++){
      int m0t = m0c + mt*16;
      f32x4 sfr[8];
      #pragma unroll
      for (int h = 0; h < 8; h++){
        short8 kf = *(const short8*)(kus + (((size_t)b*8 + h)*N_ + m0t + c)*D_ + q*8);
        f32x4 z = {0.f,0.f,0.f,0.f};
        sfr[h] = __builtin_amdgcn_mfma_f32_16x16x32_bf16(kf, qfrag[h], z, 0, 0, 0);
      }
      // interaction for this lane's 4 elements (m = m0t + q*4 + r, n = n_g)
      float ifl[4][8];
      #pragma unroll
      for (int r = 0; r < 4; r++){
        int m = m0t + q*4 + r;
        size_t i8 = ((size_t)b*N_ + n_g)*N_ + m;
        if (fint){
          uint4 iv = *(const uint4*)((const unsigned short*)inter + i8*8);
          ifl[r][0]=us2f(iv.x&0xffffu); ifl[r][1]=us2f(iv.x>>16);
          ifl[r][2]=us2f(iv.y&0xffffu); ifl[r][3]=us2f(iv.y>>16);
          ifl[r][4]=us2f(iv.z&0xffffu); ifl[r][5]=us2f(iv.z>>16);
          ifl[r][6]=us2f(iv.w&0xffffu); ifl[r][7]=us2f(iv.w>>16);
        } else {
          const float* fp = (const float*)inter + i8*8;
          #pragma unroll
          for (int g = 0; g < 8; g++) ifl[r][g] = fp[g];
        }
      }
      #pragma unroll
      for (int g = 0; g < 8; g++){
        float sv[4];
        #pragma unroll
        for (int r = 0; r < 4; r++){
          int m = m0t + q*4 + r;
          float v = b1v[g] + ifl[r][g];
          #pragma unroll
          for (int h = 0; h < 8; h++) v += sfr[h][r] * w1s[h*8 + g];
          bool ok = (n_g >= len) || (m < len);
          sv[r] = ok ? v : -1e30f;
        }
        float tmax = fmaxf(fmaxf(sv[0], sv[1]), fmaxf(sv[2], sv[3]));
        float Mn = fmaxf(M[g], tmax);
        float f = __expf(M[g] - Mn);
        L[g] = L[g]*f + __expf(sv[0]-Mn) + __expf(sv[1]-Mn) + __expf(sv[2]-Mn) + __expf(sv[3]-Mn);
        M[g] = Mn;
      }
    }
  }
  // combine across quads (lanes with same lane&15)
  #pragma unroll
  for (int g = 0; g < 8; g++){
    #pragma unroll
    for (int sft = 16; sft <= 32; sft <<= 1){
      float Mo = __shfl_xor(M[g], sft);
      float Lo = __shfl_xor(L[g], sft);
      float Mn = fmaxf(M[g], Mo);
      L[g] = L[g]*__expf(M[g]-Mn) + Lo*__expf(Mo-Mn);
      M[g] = Mn;
    }
  }
  if (lane < 16){
    #pragma unroll
    for (int g = 0; g < 8; g++){ swM[w][g][c] = M[g]; swL[w][g][c] = L[g]; }
  }
  __syncthreads();
  if (t < 128){
    int g = t >> 4, nl = t & 15;
    float Mf = fmaxf(fmaxf(swM[0][g][nl], swM[1][g][nl]), fmaxf(swM[2][g][nl], swM[3][g][nl]));
    float Lf = 0.f;
    #pragma unroll
    for (int wv = 0; wv < 4; wv++) Lf += swL[wv][g][nl] * __expf(swM[wv][g][nl] - Mf);
    stats[((size_t)b*8 + g)*N_ + n0 + nl] = make_float2(Mf, Lf);
  }
}

// ============ MFMA attention pass B: scores -> p -> th2 mix -> PV ============
__global__ __launch_bounds__(256) void k_attn2(const bf16* qb, const bf16* kb, const bf16* vb,
                                               const void* Wt1, const void* bt1,
                                               const void* Wt2, const void* bt2,
                                               const void* inter, const int* flags,
                                               const int* lengths, const float2* stats,
                                               const float* vsum, float* aobuf){
  __shared__ unsigned short a2s[4][8][640];   // [wave][head][n*40 + m], stride 40 hw
  __shared__ unsigned short vts[4][1280];     // [wave][d*40 + m]
  __shared__ float w1s[64], w2s[64], b1v[8], b2v[8];
  __shared__ float moff[8][16];
  __shared__ float vsumS[8][32];
  __shared__ float osum[4][528];              // [wave][n*33 + d]
  int fw1 = flags[5], fb1 = flags[6], fw2 = flags[7], fb2 = flags[8], fint = flags[2];
  int t = threadIdx.x;
  int ntile = blockIdx.x, b = blockIdx.y;
  int n0 = ntile * 16;
  int len = lengths[b];
  if (t < 64){ w1s[t] = ldf(Wt1, t, fw1) * 0.17677669529663687f; w2s[t] = ldf(Wt2, t, fw2); }
  if (t < 8){ b1v[t] = ldf(bt1, t, fb1); b2v[t] = ldf(bt2, t, fb2); }
  if (t < 128){
    int g = t >> 4, nl = t & 15;
    float2 st = stats[((size_t)b*8 + g)*N_ + n0 + nl];
    moff[g][nl] = st.x + __logf(st.y);       // p = exp(s - moff)
  }
  {
    int g = t >> 5, d = t & 31;
    vsumS[g][d] = vsum[((size_t)b*8 + g)*D_ + d];
  }
  __syncthreads();
  int lane = t & 63, w = t >> 6;
  int c = lane & 15, q = lane >> 4;
  const unsigned short* qus = (const unsigned short*)qb;
  const unsigned short* kus = (const unsigned short*)kb;
  const unsigned short* vus = (const unsigned short*)vb;
  short8 qfrag[8];
  #pragma unroll
  for (int h = 0; h < 8; h++)
    qfrag[h] = *(const short8*)(qus + (((size_t)b*8 + h)*N_ + n0 + c)*D_ + q*8);
  float moffreg[8][4];
  #pragma unroll
  for (int g = 0; g < 8; g++)
    #pragma unroll
    for (int r = 0; r < 4; r++) moffreg[g][r] = moff[g][q*4 + r];
  f32x4 acc[8][2];
  #pragma unroll
  for (int gg = 0; gg < 8; gg++){ f32x4 z = {0.f,0.f,0.f,0.f}; acc[gg][0] = z; acc[gg][1] = z; }

  for (int ci = 0; ci < 8; ci++){
    int m0c = w*256 + ci*32;
    // --- scores + mix + exp + th2-mix -> A2 (wave-private LDS) ---
    #pragma unroll
    for (int mt = 0; mt < 2; mt++){
      int m0t = m0c + mt*16;
      f32x4 sfr[8];
      #pragma unroll
      for (int h = 0; h < 8; h++){
        short8 kf = *(const short8*)(kus + (((size_t)b*8 + h)*N_ + m0t + c)*D_ + q*8);
        f32x4 z = {0.f,0.f,0.f,0.f};
        sfr[h] = __builtin_amdgcn_mfma_f32_16x16x32_bf16(qfrag[h], kf, z, 0, 0, 0);
      }
      int m_g = m0t + c;                     // this lane's score column
      bool mok = (m_g < len);
      #pragma unroll
      for (int r = 0; r < 4; r++){
        int n_l = q*4 + r, n_gg = n0 + n_l;
        size_t i8 = ((size_t)b*N_ + n_gg)*N_ + m_g;
        float ifl[8];
        if (fint){
          uint4 iv = *(const uint4*)((const unsigned short*)inter + i8*8);
          ifl[0]=us2f(iv.x&0xffffu); ifl[1]=us2f(iv.x>>16);
          ifl[2]=us2f(iv.y&0xffffu); ifl[3]=us2f(iv.y>>16);
          ifl[4]=us2f(iv.z&0xffffu); ifl[5]=us2f(iv.z>>16);
          ifl[6]=us2f(iv.w&0xffffu); ifl[7]=us2f(iv.w>>16);
        } else {
          const float* fp = (const float*)inter + i8*8;
          #pragma unroll
          for (int g = 0; g < 8; g++) ifl[g] = fp[g];
        }
        bool ok = (n_gg >= len) || mok;
        float p[8];
        #pragma unroll
        for (int g = 0; g < 8; g++){
          float v = b1v[g] + ifl[g];
          #pragma unroll
          for (int h = 0; h < 8; h++) v += sfr[h][r] * w1s[h*8 + g];
          v = ok ? v : -1e30f;
          p[g] = __expf(v - moffreg[g][r]);
        }
        #pragma unroll
        for (int gg = 0; gg < 8; gg++){
          float a2 = 0.f;
          #pragma unroll
          for (int g = 0; g < 8; g++) a2 += p[g] * w2s[g*8 + gg];
          a2s[w][gg][n_l*40 + mt*16 + c] = f2bu(a2);
        }
      }
    }
    // --- PV per head: V^T through wave-private LDS, 2 MFMAs (d halves) ---
    #pragma unroll
    for (int gg = 0; gg < 8; gg++){
      short8 v0 = *(const short8*)(vus + (((size_t)b*8 + gg)*N_ + m0c + c)*D_ + q*8);
      short8 v1 = *(const short8*)(vus + (((size_t)b*8 + gg)*N_ + m0c + 16 + c)*D_ + q*8);
      #pragma unroll
      for (int j = 0; j < 8; j++){
        vts[w][(q*8 + j)*40 + c]      = (unsigned short)v0[j];
        vts[w][(q*8 + j)*40 + 16 + c] = (unsigned short)v1[j];
      }
      short8 af  = *(const short8*)&a2s[w][gg][c*40 + q*8];
      short8 bf0 = *(const short8*)&vts[w][c*40 + q*8];
      short8 bf1 = *(const short8*)&vts[w][(16 + c)*40 + q*8];
      acc[gg][0] = __builtin_amdgcn_mfma_f32_16x16x32_bf16(af, bf0, acc[gg][0], 0, 0, 0);
      acc[gg][1] = __builtin_amdgcn_mfma_f32_16x16x32_bf16(af, bf1, acc[gg][1], 0, 0, 0);
    }
  }
  // --- epilogue: reduce 4 waves' partial O, add bt2 * Vsum, store aobuf f32 ---
  for (int gg = 0; gg < 8; gg++){
    #pragma unroll
    for (int dt = 0; dt < 2; dt++)
      #pragma unroll
      for (int r = 0; r < 4; r++)
        osum[w][(q*4 + r)*33 + dt*16 + c] = acc[gg][dt][r];
    __syncthreads();
    #pragma unroll
    for (int e = t; e < 512; e += 256){
      int nl = e >> 5, d = e & 31;
      float val = osum[0][nl*33 + d] + osum[1][nl*33 + d]
                + osum[2][nl*33 + d] + osum[3][nl*33 + d]
                + b2v[gg] * vsumS[gg][d];
      aobuf[((size_t)b*N_ + n0 + nl)*C_ + gg*D_ + d] = val;
    }
    __syncthreads();
  }
}

// ---------------- launcher ----------------
extern "C" void kernel_launch(void* const* d_in, const int* in_sizes, int n_in,
                              void* d_out, int out_size, void* d_ws, size_t ws_size,
                              hipStream_t stream) {
  Ptrs ptrs;
  for (int i = 0; i < 22; i++) ptrs.p[i] = d_in[i];
  const unsigned char* mask = (const unsigned char*)d_in[1];

  char* ws = (char*)d_ws;
  size_t o = 0;
  size_t o_flags = o; o += 256;
  size_t o_len   = o; o += 256;
  size_t o_stats = o; o += (size_t)B_*H_*N_*sizeof(float2);   // 512 KB
  size_t o_vsum  = o; o += (size_t)B_*H_*D_*4;                // 8 KB
  size_t o_h     = o; o += (size_t)B_*N_*C_*2;                // 4 MB bf16
  size_t o_q     = o; o += (size_t)B_*N_*C_*2;
  size_t o_k     = o; o += (size_t)B_*N_*C_*2;
  size_t o_v     = o; o += (size_t)B_*N_*C_*2;
  size_t o_ao    = o; o += (size_t)B_*N_*C_*4;                // 8 MB f32
  size_t o_x     = o; o += (size_t)B_*N_*C_*4;                // 8 MB f32
  size_t o_f     = o; o += (size_t)B_*N_*F_*2;                // 11 MB bf16

  int*    flags   = (int*)(ws + o_flags);
  int*    lengths = (int*)(ws + o_len);
  float2* stats   = (float2*)(ws + o_stats);
  float*  vsum    = (float*)(ws + o_vsum);
  bf16*   hbuf    = (bf16*)(ws + o_h);
  bf16*   qbuf    = (bf16*)(ws + o_q);
  bf16*   kbuf    = (bf16*)(ws + o_k);
  bf16*   vbuf    = (bf16*)(ws + o_v);
  float*  aobuf   = (float*)(ws + o_ao);
  float*  xbuf    = (float*)(ws + o_x);
  bf16*   fbuf    = (bf16*)(ws + o_f);

  k_sniff<<<1, 64, 0, stream>>>(ptrs, flags);
  k_lengths<<<8, 256, 0, stream>>>(mask, lengths);
  k_ln<<<B_*N_, 256, 0, stream>>>(d_in[0], flags, 0, d_in[11], 11, d_in[12], 12, hbuf, 1, C_);
  k_qkv<<<dim3(128, 12), 256, 0, stream>>>(hbuf, d_in[3], d_in[4], flags, qbuf, kbuf, vbuf);
  k_vsum<<<64, 256, 0, stream>>>(vbuf, vsum);
  k_stats2<<<dim3(64, 8), 256, 0, stream>>>(qbuf, kbuf, d_in[5], d_in[6], d_in[2],
                                            flags, lengths, stats);
  k_attn2<<<dim3(64, 8), 256, 0, stream>>>(qbuf, kbuf, vbuf, d_in[5], d_in[6], d_in[7], d_in[8],
                                           d_in[2], flags, lengths, stats, vsum, aobuf);
  k_outproj<<<dim3(128, 4), 256, 0, stream>>>(aobuf, d_in[9], d_in[10], d_in[0], d_in[15], flags, xbuf);
  k_ln<<<B_*N_, 256, 0, stream>>>(xbuf, flags, -1, d_in[13], 13, d_in[14], 14, hbuf, 1, C_);
  k_ffn1<<<dim3(128, 11), 256, 0, stream>>>(hbuf, d_in[17], d_in[18], flags, fbuf);
  k_ln<<<B_*N_, 256, 0, stream>>>(fbuf, flags, -2, d_in[20], 20, d_in[21], 21, fbuf, 1, F_);
  k_down<<<dim3(128, 4), 256, 0, stream>>>(fbuf, d_in[19], xbuf, d_in[16], flags, d_out);
}